// Round 2
// baseline (1000.672 us; speedup 1.0000x reference)
//
#include <hip/hip_runtime.h>

#define DEVI static __device__ __forceinline__

typedef __bf16 bf16x8 __attribute__((ext_vector_type(8)));
typedef float  f32x4  __attribute__((ext_vector_type(4)));

enum { OM_F32 = 0, OM_BF16T = 1, OM_BF16 = 2, OM_ATOM = 3, OM_SMST = 4 };

DEVI unsigned short f2bf(float f) {
  unsigned int u = __float_as_uint(f);
  u = (u + 0x7FFFu + ((u >> 16) & 1u)) >> 16;
  return (unsigned short)u;
}
DEVI float bf2f(unsigned short h) { return __uint_as_float(((unsigned int)h) << 16); }
DEVI void splitf(float v, unsigned short& hi, unsigned short& lo) {
  unsigned short h = f2bf(v);
  hi = h;
  lo = f2bf(v - bf2f(h));
}

#define GLD_LDS(gp, lp)                                                            \
  __builtin_amdgcn_global_load_lds((const __attribute__((address_space(1))) void*)(gp), \
                                   (__attribute__((address_space(3))) void*)(lp), 16, 0, 0)

// ------------------------------------------------------------------
// small kernels
// ------------------------------------------------------------------
__global__ void k_zero4(float* __restrict__ p, int n4) {
  int i = blockIdx.x * 256 + threadIdx.x;
  if (i < n4) ((float4*)p)[i] = float4{0.f, 0.f, 0.f, 0.f};
}

__global__ void k_cvt_pair(const float* __restrict__ src, unsigned short* __restrict__ hi,
                           unsigned short* __restrict__ lo, int n4) {
  int i = blockIdx.x * 256 + threadIdx.x;
  if (i >= n4) return;
  float4 v = ((const float4*)src)[i];
  ushort4 h, l;
  splitf(v.x, h.x, l.x);
  splitf(v.y, h.y, l.y);
  splitf(v.z, h.z, l.z);
  splitf(v.w, h.w, l.w);
  ((ushort4*)hi)[i] = h;
  ((ushort4*)lo)[i] = l;
}

// all 5 weight matrices in one dispatch (quad-indexed ranges)
__global__ void k_cvt_w(const float* __restrict__ W1, const float* __restrict__ W2,
                        const float* __restrict__ Wf1, const float* __restrict__ Wf2,
                        const float* __restrict__ Wf4, unsigned short* __restrict__ w1h,
                        unsigned short* __restrict__ w1l, unsigned short* __restrict__ w2h,
                        unsigned short* __restrict__ w2l, unsigned short* __restrict__ wf1h,
                        unsigned short* __restrict__ wf1l, unsigned short* __restrict__ wf2h,
                        unsigned short* __restrict__ wf2l, unsigned short* __restrict__ wf4h,
                        unsigned short* __restrict__ wf4l) {
  int gid = blockIdx.x * 256 + threadIdx.x;  // < 98304 quads
  const float* s;
  unsigned short *h, *l;
  int off;
  if (gid < 16384)      { s = W1;  h = w1h;  l = w1l;  off = 0; }
  else if (gid < 32768) { s = W2;  h = w2h;  l = w2l;  off = 16384; }
  else if (gid < 49152) { s = Wf1; h = wf1h; l = wf1l; off = 32768; }
  else if (gid < 65536) { s = Wf2; h = wf2h; l = wf2l; off = 49152; }
  else                  { s = Wf4; h = wf4h; l = wf4l; off = 65536; }
  int i = gid - off;
  float4 v = ((const float4*)s)[i];
  ushort4 hh, ll;
  splitf(v.x, hh.x, ll.x);
  splitf(v.y, hh.y, ll.y);
  splitf(v.z, hh.z, ll.z);
  splitf(v.w, hh.w, ll.w);
  ((ushort4*)h)[i] = hh;
  ((ushort4*)l)[i] = ll;
}

// adj -> bf16 (hi only) + exact per-row rounding-error sum (for rank-1 correction)
__global__ void k_cvt_adj(const float* __restrict__ adj, unsigned short* __restrict__ ah,
                          float* __restrict__ rowErr) {
  int row = blockIdx.x;
  int t = threadIdx.x;
  const float4* src = (const float4*)(adj + (size_t)row * 8192);
  ushort4* dst = (ushort4*)(ah + (size_t)row * 8192);
  float err = 0.f;
#pragma unroll
  for (int c = 0; c < 8; ++c) {
    int i = c * 256 + t;
    float4 v = src[i];
    ushort4 h;
    h.x = f2bf(v.x); h.y = f2bf(v.y); h.z = f2bf(v.z); h.w = f2bf(v.w);
    err += (v.x - bf2f(h.x)) + (v.y - bf2f(h.y)) + (v.z - bf2f(h.z)) + (v.w - bf2f(h.w));
    dst[i] = h;
  }
#pragma unroll
  for (int o = 1; o < 64; o <<= 1) err += __shfl_xor(err, o);
  __shared__ float se[4];
  if ((t & 63) == 0) se[t >> 6] = err;
  __syncthreads();
  if (t == 0) rowErr[row] = se[0] + se[1] + se[2] + se[3];
}

// read atomic fp32 accumulator + rank-1 adj-rounding correction (+optional relu), emit split bf16
template <int RELU, int WF32>
__global__ void k_red(const float* __restrict__ P, const float* __restrict__ rowErr,
                      const float* __restrict__ ybar, float* __restrict__ zf,
                      unsigned short* __restrict__ oh, unsigned short* __restrict__ ol) {
  int gid = blockIdx.x * 256 + threadIdx.x;  // < 8192*256
  int i = gid >> 8, j = gid & 255;
  float v = P[gid] + rowErr[i] * ybar[j];
  if (RELU) v = fmaxf(v, 0.f);
  if (WF32) zf[gid] = v;
  unsigned short h, l;
  splitf(v, h, l);
  oh[gid] = h;
  ol[gid] = l;
}

__global__ void k_gather_sl(const int* __restrict__ last, const float* __restrict__ zf,
                            float* __restrict__ sl, unsigned short* __restrict__ slh,
                            unsigned short* __restrict__ sll, float* __restrict__ sg) {
  int b = blockIdx.x, t = threadIdx.x;
  float v = zf[(size_t)last[b] * 256 + t];
  sl[b * 256 + t] = v;
  unsigned short h, l;
  splitf(v, h, l);
  slh[b * 256 + t] = h;
  sll[b * 256 + t] = l;
  sg[b * 256 + t] = 0.f;  // zero the scatter-add target (fused k_zero)
}

// alpha = sigmoid(q1[idx[i]]+q2[i]) . Wf3 ; sg[idx[i]] += alpha * z[i]
__global__ void k_alpha(const int* __restrict__ idx, const float* __restrict__ q1s,
                        const float* __restrict__ q2, const float* __restrict__ w3,
                        const float* __restrict__ zf, float* __restrict__ sg) {
  int i = blockIdx.x * 4 + (threadIdx.x >> 6);
  int lane = threadIdx.x & 63;
  int seg = idx[i];
  int k = lane * 4;
  float4 a = *(const float4*)(q1s + (size_t)seg * 256 + k);
  float4 b = *(const float4*)(q2 + (size_t)i * 256 + k);
  float4 w = *(const float4*)(w3 + k);
  float s = w.x / (1.f + __expf(-(a.x + b.x))) + w.y / (1.f + __expf(-(a.y + b.y))) +
            w.z / (1.f + __expf(-(a.z + b.z))) + w.w / (1.f + __expf(-(a.w + b.w)));
#pragma unroll
  for (int o = 1; o < 64; o <<= 1) s += __shfl_xor(s, o);
  float4 z4 = *(const float4*)(zf + (size_t)i * 256 + k);
  float* d = sg + (size_t)seg * 256 + k;
  atomicAdd(d + 0, s * z4.x);
  atomicAdd(d + 1, s * z4.y);
  atomicAdd(d + 2, s * z4.z);
  atomicAdd(d + 3, s * z4.w);
}

__global__ void k_concat(const float* __restrict__ sl, const float* __restrict__ sg,
                         unsigned short* __restrict__ sh, unsigned short* __restrict__ slo) {
  int b = blockIdx.x, t = threadIdx.x;
  float v1 = sl[b * 256 + t];
  float v2 = sg[b * 256 + t];
  int o1 = b * 512 + t, o2 = o1 + 256;
  unsigned short h, l;
  splitf(v1, h, l); sh[o1] = h; slo[o1] = l;
  splitf(v2, h, l); sh[o2] = h; slo[o2] = l;
}

__global__ void k_smred(const float* __restrict__ pM, const float* __restrict__ pS,
                        float* __restrict__ mA, float* __restrict__ sA, int nt, int N) {
  __shared__ float lm[256], ls[256];
  int b = blockIdx.x;
  int t = threadIdx.x;
  float mx = -3.0e38f, sm = 0.f;
  for (int i = t; i < nt; i += 256) {
    float m = pM[(size_t)i * N + b];
    float s = pS[(size_t)i * N + b];
    if (m > mx) { sm = sm * __expf(mx - m) + s; mx = m; }
    else        { sm += s * __expf(m - mx); }
  }
  lm[t] = mx; ls[t] = sm;
  __syncthreads();
  for (int off = 128; off > 0; off >>= 1) {
    if (t < off) {
      float m2 = lm[t + off], s2 = ls[t + off];
      float mN = fmaxf(lm[t], m2);
      ls[t] = ls[t] * __expf(lm[t] - mN) + s2 * __expf(m2 - mN);
      lm[t] = mN;
    }
    __syncthreads();
  }
  if (t == 0) { mA[b] = lm[0]; sA[b] = ls[0]; }
}

__global__ void k_norm(float* __restrict__ out, const float* __restrict__ mA,
                       const float* __restrict__ sA) {
  size_t gid = (size_t)blockIdx.x * 256 + threadIdx.x;
  size_t e = gid * 4;
  int b = (int)(e / 100000);
  float m = mA[b];
  float inv = 1.0f / sA[b];
  float4 v = *(float4*)(out + e);
  v.x = __expf(v.x - m) * inv;
  v.y = __expf(v.y - m) * inv;
  v.z = __expf(v.z - m) * inv;
  v.w = __expf(v.w - m) * inv;
  *(float4*)(out + e) = v;
}

// ------------------------------------------------------------------
// GEMM: C[M,N] = A[M,K] @ B[N,K]^T  (bf16, optional hi/lo split operands)
// 128x128 tile, BK=64, 4 waves (2x2 of 64x64), 16x16x32 MFMA,
// global_load_lds width-16 staging, XOR-swizzled LDS (<=2-way bank alias).
// grid: x = N/128 (fast, for A-tile L2 reuse), y = M/128, z = split-K.
// OM_BF16T epilogue also accumulates column means into `pM` (=ybar) via atomics.
// ------------------------------------------------------------------
template <int ASPL, int BSPL, int OMODE, int HAS_BIAS, int MINW, int GATHER>
__global__ __launch_bounds__(256, MINW) void gemm_bt(
    const unsigned short* __restrict__ Ah, const unsigned short* __restrict__ Al,
    const unsigned short* __restrict__ Bh, const unsigned short* __restrict__ Bl,
    const float* __restrict__ bias, float* __restrict__ outF,
    unsigned short* __restrict__ outH, unsigned short* __restrict__ outL,
    float* __restrict__ pM, float* __restrict__ pS, const int* __restrict__ gidx, int M, int N,
    int lda, int ldb, long long ldo, int kStart, int kLen) {
  __shared__ unsigned short lds[(2 + ASPL + BSPL) * 8192];
  unsigned short* ldsA = lds;
  unsigned short* ldsAl = lds + 8192;  // valid iff ASPL
  unsigned short* ldsB = lds + (1 + ASPL) * 8192;
  unsigned short* ldsBl = lds + (2 + ASPL) * 8192;  // valid iff BSPL

  const int tid = threadIdx.x;
  const int lane = tid & 63;
  const int wave = tid >> 6;
  const int wrow = wave >> 1;
  const int wcol = wave & 1;
  const int l15 = lane & 15;
  const int lkg = lane >> 4;
  const int n0 = blockIdx.x * 128;
  const int m0 = blockIdx.y * 128;
  const int ks = kStart + blockIdx.z * kLen;

  // hoisted A-row (with optional gather indirection) and B-row per staging chunk
  int ga[4], gb[4];
#pragma unroll
  for (int c = 0; c < 4; ++c) {
    int row = (c * 256 + tid) >> 3;
    int ra = m0 + row;
    if (ra >= M) ra = M - 1;
    ga[c] = GATHER ? gidx[ra] : ra;
    gb[c] = n0 + row;
  }

  f32x4 acc[4][4];
#pragma unroll
  for (int a = 0; a < 4; ++a)
#pragma unroll
    for (int b = 0; b < 4; ++b) acc[a][b] = f32x4{0.f, 0.f, 0.f, 0.f};

  for (int k0 = ks; k0 < ks + kLen; k0 += 64) {
    // ---- stage: LDS slot (row,kc) holds global k-chunk (kc ^ (row&7)), 8 bf16/slot
#pragma unroll
    for (int c = 0; c < 4; ++c) {
      int s = c * 256 + tid;
      int row = s >> 3;
      int kc = s & 7;
      int kel = k0 + ((kc ^ (row & 7)) << 3);
      int lofs = (c * 256 + wave * 64) << 3;  // wave-uniform base
      GLD_LDS(Ah + (size_t)ga[c] * lda + kel, ldsA + lofs);
      if (ASPL) GLD_LDS(Al + (size_t)ga[c] * lda + kel, ldsAl + lofs);
      GLD_LDS(Bh + (size_t)gb[c] * ldb + kel, ldsB + lofs);
      if (BSPL) GLD_LDS(Bl + (size_t)gb[c] * ldb + kel, ldsBl + lofs);
    }
    __syncthreads();  // drains vmcnt (LDS-DMA) + orders vs compute
    // ---- compute
#pragma unroll
    for (int kk = 0; kk < 2; ++kk) {
      bf16x8 fa[4], fb[4], fal[4], fbl[4];
#pragma unroll
      for (int t = 0; t < 4; ++t) {
        int mm = (wrow << 6) + (t << 4) + l15;
        int kc = (kk << 2) + lkg;
        int sa = ((mm << 3) + (kc ^ (mm & 7))) << 3;
        fa[t] = *(const bf16x8*)(ldsA + sa);
        if (ASPL) fal[t] = *(const bf16x8*)(ldsAl + sa);
        int nn = (wcol << 6) + (t << 4) + l15;
        int sb = ((nn << 3) + (kc ^ (nn & 7))) << 3;
        fb[t] = *(const bf16x8*)(ldsB + sb);
        if (BSPL) fbl[t] = *(const bf16x8*)(ldsBl + sb);
      }
#pragma unroll
      for (int tm = 0; tm < 4; ++tm)
#pragma unroll
        for (int tn = 0; tn < 4; ++tn) {
          acc[tm][tn] = __builtin_amdgcn_mfma_f32_16x16x32_bf16(fa[tm], fb[tn], acc[tm][tn], 0, 0, 0);
          if (BSPL)
            acc[tm][tn] = __builtin_amdgcn_mfma_f32_16x16x32_bf16(fa[tm], fbl[tn], acc[tm][tn], 0, 0, 0);
          if (ASPL)
            acc[tm][tn] = __builtin_amdgcn_mfma_f32_16x16x32_bf16(fal[tm], fb[tn], acc[tm][tn], 0, 0, 0);
        }
    }
    __syncthreads();
  }

  // ---- epilogue. C/D layout: col = lane&15 (N), row = (lane>>4)*4 + reg (M)
  const int mb = m0 + (wrow << 6);
  const int nb = n0 + (wcol << 6);

  if constexpr (OMODE == OM_ATOM) {
#pragma unroll
    for (int tm = 0; tm < 4; ++tm) {
      const int mg = mb + (tm << 4) + (lkg << 2);
#pragma unroll
      for (int tn = 0; tn < 4; ++tn) {
        const int ng = nb + (tn << 4) + l15;
#pragma unroll
        for (int r = 0; r < 4; ++r) atomicAdd(outF + (size_t)(mg + r) * N + ng, acc[tm][tn][r]);
      }
    }
  } else if constexpr (OMODE == OM_F32) {
#pragma unroll
    for (int tm = 0; tm < 4; ++tm) {
      const int mg = mb + (tm << 4) + (lkg << 2);
#pragma unroll
      for (int tn = 0; tn < 4; ++tn) {
        const int ng = nb + (tn << 4) + l15;
        const float bv = HAS_BIAS ? bias[ng] : 0.f;
#pragma unroll
        for (int r = 0; r < 4; ++r)
          outF[(size_t)(mg + r) * (size_t)ldo + ng] = acc[tm][tn][r] + bv;
      }
    }
  } else if constexpr (OMODE == OM_BF16) {
#pragma unroll
    for (int tm = 0; tm < 4; ++tm) {
      const int mg = mb + (tm << 4) + (lkg << 2);
#pragma unroll
      for (int tn = 0; tn < 4; ++tn) {
        const int ng = nb + (tn << 4) + l15;
        const float bv = HAS_BIAS ? bias[ng] : 0.f;
#pragma unroll
        for (int r = 0; r < 4; ++r) {
          unsigned short h, l;
          splitf(acc[tm][tn][r] + bv, h, l);
          outH[(size_t)(mg + r) * (size_t)ldo + ng] = h;
          outL[(size_t)(mg + r) * (size_t)ldo + ng] = l;
        }
      }
    }
  } else if constexpr (OMODE == OM_BF16T) {
    // write transposed: out[n][m]; also accumulate column means into pM (=ybar)
    float colp[4];
#pragma unroll
    for (int tn = 0; tn < 4; ++tn) {
      const int ng = nb + (tn << 4) + l15;
      const float bv = HAS_BIAS ? bias[ng] : 0.f;
      float cp = 0.f;
#pragma unroll
      for (int tm = 0; tm < 4; ++tm) {
        const int m4 = mb + (tm << 4) + (lkg << 2);
        ushort4 h4, l4;
        float v0 = acc[tm][tn][0] + bv, v1 = acc[tm][tn][1] + bv;
        float v2 = acc[tm][tn][2] + bv, v3 = acc[tm][tn][3] + bv;
        cp += (v0 + v1) + (v2 + v3);
        splitf(v0, h4.x, l4.x);
        splitf(v1, h4.y, l4.y);
        splitf(v2, h4.z, l4.z);
        splitf(v3, h4.w, l4.w);
        *(ushort4*)(outH + (size_t)ng * (size_t)ldo + m4) = h4;
        *(ushort4*)(outL + (size_t)ng * (size_t)ldo + m4) = l4;
      }
      colp[tn] = cp;
    }
#pragma unroll
    for (int tn = 0; tn < 4; ++tn) {
      float cp = colp[tn];
      cp += __shfl_xor(cp, 16);
      cp += __shfl_xor(cp, 32);
      if (lkg == 0) atomicAdd(pM + nb + (tn << 4) + l15, cp * (1.f / 8192.f));
    }
  } else if constexpr (OMODE == OM_SMST) {
    // store raw logits transposed: outF[b][i] (ldo = M stride of out rows),
    // plus per-(rowtile, col) online-softmax partials {max, sumexp}.
    float cm[4], cs[4];
#pragma unroll
    for (int tn = 0; tn < 4; ++tn) {
      const int ng = nb + (tn << 4) + l15;
#pragma unroll
      for (int tm = 0; tm < 4; ++tm) {
        const int m4 = mb + (tm << 4) + (lkg << 2);
        if (m4 < M) {
          float4 v4 = {acc[tm][tn][0], acc[tm][tn][1], acc[tm][tn][2], acc[tm][tn][3]};
          *(float4*)(outF + (size_t)ng * (size_t)ldo + m4) = v4;
        }
      }
      float mx = -3.0e38f;
#pragma unroll
      for (int tm = 0; tm < 4; ++tm) {
        const int m4 = mb + (tm << 4) + (lkg << 2);
        if (m4 < M) {
#pragma unroll
          for (int r = 0; r < 4; ++r) mx = fmaxf(mx, acc[tm][tn][r]);
        }
      }
      mx = fmaxf(mx, __shfl_xor(mx, 16));
      mx = fmaxf(mx, __shfl_xor(mx, 32));
      float sm = 0.f;
#pragma unroll
      for (int tm = 0; tm < 4; ++tm) {
        const int m4 = mb + (tm << 4) + (lkg << 2);
        if (m4 < M) {
#pragma unroll
          for (int r = 0; r < 4; ++r) sm += __expf(acc[tm][tn][r] - mx);
        }
      }
      sm += __shfl_xor(sm, 16);
      sm += __shfl_xor(sm, 32);
      cm[tn] = mx;
      cs[tn] = sm;
    }
    float* sf = (float*)lds;  // LDS free after last loop barrier
    if (lkg == 0) {
#pragma unroll
      for (int tn = 0; tn < 4; ++tn) {
        int col = (wcol << 6) + (tn << 4) + l15;
        sf[(wrow << 7) + col] = cm[tn];
        sf[256 + (wrow << 7) + col] = cs[tn];
      }
    }
    __syncthreads();
    if (tid < 128) {
      float ma = sf[tid], mb2 = sf[128 + tid];
      float sa2 = sf[256 + tid], sb2 = sf[384 + tid];
      float mv = fmaxf(ma, mb2);
      float sv = sa2 * __expf(ma - mv) + sb2 * __expf(mb2 - mv);
      pM[(size_t)blockIdx.y * N + n0 + tid] = mv;
      pS[(size_t)blockIdx.y * N + n0 + tid] = sv;
    }
  }
}

// ------------------------------------------------------------------
extern "C" void kernel_launch(void* const* d_in, const int* in_sizes, int n_in, void* d_out,
                              int out_size, void* d_ws, size_t ws_size, hipStream_t stream) {
  (void)in_sizes; (void)n_in; (void)out_size;
  const float* adj = (const float*)d_in[0];
  const int* items = (const int*)d_in[1];
  const int* last = (const int*)d_in[2];
  const int* idx = (const int*)d_in[3];
  const float* emb = (const float*)d_in[4];
  const float* W1 = (const float*)d_in[5];
  const float* b1 = (const float*)d_in[6];
  const float* W2 = (const float*)d_in[7];
  const float* b2 = (const float*)d_in[8];
  const float* Wf1 = (const float*)d_in[9];
  const float* bf1 = (const float*)d_in[10];
  const float* Wf2 = (const float*)d_in[11];
  const float* bf2 = (const float*)d_in[12];
  const float* Wf3 = (const float*)d_in[13];
  const float* Wf4 = (const float*)d_in[14];
  const float* bf4 = (const float*)d_in[15];
  float* out = (float*)d_out;

  char* base = (char*)d_ws;
  size_t used = 0;
  auto alloc = [&](size_t bytes) -> char* {
    char* r = base + used;
    used += (bytes + 255) & ~(size_t)255;
    return r;
  };
  unsigned short* adjh = (unsigned short*)alloc((size_t)8192 * 8192 * 2);
  unsigned short* embh = (unsigned short*)alloc((size_t)100000 * 256 * 2);
  unsigned short* embl = (unsigned short*)alloc((size_t)100000 * 256 * 2);
  float* rowErrA = (float*)alloc(8192 * 4);
  // --- contiguous zero-init region: hpre, zpre, ybar1, ybar2 (all 256B-multiples)
  float* hpre = (float*)alloc((size_t)8192 * 256 * 4);
  float* zpre = (float*)alloc((size_t)8192 * 256 * 4);
  float* ybar1 = (float*)alloc(256 * 4);
  float* ybar2 = (float*)alloc(256 * 4);
  // ---
  unsigned short* w1h = (unsigned short*)alloc(65536 * 2);
  unsigned short* w1l = (unsigned short*)alloc(65536 * 2);
  unsigned short* w2h = (unsigned short*)alloc(65536 * 2);
  unsigned short* w2l = (unsigned short*)alloc(65536 * 2);
  unsigned short* wf1h = (unsigned short*)alloc(65536 * 2);
  unsigned short* wf1l = (unsigned short*)alloc(65536 * 2);
  unsigned short* wf2h = (unsigned short*)alloc(65536 * 2);
  unsigned short* wf2l = (unsigned short*)alloc(65536 * 2);
  unsigned short* wf4h = (unsigned short*)alloc(131072 * 2);
  unsigned short* wf4l = (unsigned short*)alloc(131072 * 2);
  unsigned short* y1Th = (unsigned short*)alloc((size_t)256 * 8192 * 2);
  unsigned short* y1Tl = (unsigned short*)alloc((size_t)256 * 8192 * 2);
  unsigned short* y2Th = (unsigned short*)alloc((size_t)256 * 8192 * 2);
  unsigned short* y2Tl = (unsigned short*)alloc((size_t)256 * 8192 * 2);
  unsigned short* hh = (unsigned short*)alloc((size_t)8192 * 256 * 2);
  unsigned short* hl = (unsigned short*)alloc((size_t)8192 * 256 * 2);
  float* zf = (float*)alloc((size_t)8192 * 256 * 4);
  unsigned short* zh = (unsigned short*)alloc((size_t)8192 * 256 * 2);
  unsigned short* zl = (unsigned short*)alloc((size_t)8192 * 256 * 2);
  float* q1s = (float*)alloc((size_t)512 * 256 * 4);
  float* q2 = (float*)alloc((size_t)8192 * 256 * 4);
  float* sl = (float*)alloc((size_t)512 * 256 * 4);
  unsigned short* slh = (unsigned short*)alloc((size_t)512 * 256 * 2);
  unsigned short* sll = (unsigned short*)alloc((size_t)512 * 256 * 2);
  float* sg = (float*)alloc((size_t)512 * 256 * 4);
  unsigned short* s_h = (unsigned short*)alloc((size_t)512 * 512 * 2);
  unsigned short* s_l = (unsigned short*)alloc((size_t)512 * 512 * 2);
  unsigned short* shh = (unsigned short*)alloc((size_t)512 * 256 * 2);
  unsigned short* shl = (unsigned short*)alloc((size_t)512 * 256 * 2);
  float* pMx = (float*)alloc((size_t)782 * 512 * 4);
  float* pSx = (float*)alloc((size_t)782 * 512 * 4);
  float* mA = (float*)alloc(512 * 4);
  float* sA = (float*)alloc(512 * 4);
  if (used > ws_size) return;  // insufficient workspace: bail (bench will flag)

  // zero hpre+zpre+ybar1+ybar2 (contiguous, 4194432 float4s)
  k_zero4<<<16385, 256, 0, stream>>>(hpre, 4194432);
  // conversions
  k_cvt_pair<<<25000, 256, 0, stream>>>(emb, embh, embl, 6400000);
  k_cvt_adj<<<8192, 256, 0, stream>>>(adj, adjh, rowErrA);
  k_cvt_w<<<384, 256, 0, stream>>>(W1, W2, Wf1, Wf2, Wf4, w1h, w1l, w2h, w2l, wf1h, wf1l, wf2h,
                                   wf2l, wf4h, wf4l);

  // y1^T = (emb[items]@W1^T + b1)^T  [256 x 8192], gather fused into A-staging; colmean->ybar1
  gemm_bt<1, 1, OM_BF16T, 1, 2, 1><<<dim3(2, 64, 1), 256, 0, stream>>>(
      embh, embl, w1h, w1l, b1, nullptr, y1Th, y1Tl, ybar1, nullptr, items, 8192, 256, 256, 256,
      8192, 0, 256);
  // h_pre = adj @ y1 (split-K=4, atomic fp32 accumulate)
  gemm_bt<0, 1, OM_ATOM, 0, 3, 0><<<dim3(2, 64, 4), 256, 0, stream>>>(
      adjh, nullptr, y1Th, y1Tl, nullptr, hpre, nullptr, nullptr, nullptr, nullptr, nullptr, 8192,
      256, 8192, 8192, 0, 0, 2048);
  k_red<1, 0><<<8192, 256, 0, stream>>>(hpre, rowErrA, ybar1, nullptr, hh, hl);  // h = relu(...)
  // y2^T = (h@W2^T + b2)^T ; colmean->ybar2
  gemm_bt<1, 1, OM_BF16T, 1, 2, 0><<<dim3(2, 64, 1), 256, 0, stream>>>(
      hh, hl, w2h, w2l, b2, nullptr, y2Th, y2Tl, ybar2, nullptr, nullptr, 8192, 256, 256, 256,
      8192, 0, 256);
  // z_pre = adj @ y2 (split-K=4, atomic)
  gemm_bt<0, 1, OM_ATOM, 0, 3, 0><<<dim3(2, 64, 4), 256, 0, stream>>>(
      adjh, nullptr, y2Th, y2Tl, nullptr, zpre, nullptr, nullptr, nullptr, nullptr, nullptr, 8192,
      256, 8192, 8192, 0, 0, 2048);
  k_red<0, 1><<<8192, 256, 0, stream>>>(zpre, rowErrA, ybar2, zf, zh, zl);

  k_gather_sl<<<512, 256, 0, stream>>>(last, zf, sl, slh, sll, sg);
  // q1 = sl@Wf1^T + bf1 ; q2 = z@Wf2^T + bf2
  gemm_bt<1, 1, OM_F32, 1, 2, 0><<<dim3(2, 4, 1), 256, 0, stream>>>(
      slh, sll, wf1h, wf1l, bf1, q1s, nullptr, nullptr, nullptr, nullptr, nullptr, 512, 256, 256,
      256, 256, 0, 256);
  gemm_bt<1, 1, OM_F32, 1, 2, 0><<<dim3(2, 64, 1), 256, 0, stream>>>(
      zh, zl, wf2h, wf2l, bf2, q2, nullptr, nullptr, nullptr, nullptr, nullptr, 8192, 256, 256,
      256, 256, 0, 256);
  k_alpha<<<2048, 256, 0, stream>>>(idx, q1s, q2, Wf3, zf, sg);
  k_concat<<<512, 256, 0, stream>>>(sl, sg, s_h, s_l);
  // sh = [sl|sg]@Wf4^T + bf4  -> split bf16 [512 x 256]
  gemm_bt<1, 1, OM_BF16, 1, 2, 0><<<dim3(2, 4, 1), 256, 0, stream>>>(
      s_h, s_l, wf4h, wf4l, bf4, nullptr, shh, shl, nullptr, nullptr, nullptr, 512, 256, 512, 512,
      256, 0, 512);
  // logits = emb @ sh^T, stored transposed fp32 into out + softmax partials
  gemm_bt<1, 1, OM_SMST, 0, 2, 0><<<dim3(4, 782, 1), 256, 0, stream>>>(
      embh, embl, shh, shl, nullptr, out, nullptr, nullptr, pMx, pSx, nullptr, 100000, 512, 256,
      256, 100000, 0, 256);
  k_smred<<<512, 256, 0, stream>>>(pMx, pSx, mA, sA, 782, 512);
  k_norm<<<50000, 256, 0, stream>>>(out, mA, sA);
}

// Round 3
// 966.861 us; speedup vs baseline: 1.0350x; 1.0350x over previous
//
#include <hip/hip_runtime.h>

#define DEVI static __device__ __forceinline__

typedef __bf16 bf16x8 __attribute__((ext_vector_type(8)));
typedef float  f32x4  __attribute__((ext_vector_type(4)));

enum { OM_F32 = 0, OM_BF16T = 1, OM_BF16 = 2, OM_ATOM = 3, OM_SMST = 4 };
enum { SWZ_NONE = 0, SWZ_ADJ = 1, SWZ_FIN = 2 };

DEVI unsigned short f2bf(float f) {
  unsigned int u = __float_as_uint(f);
  u = (u + 0x7FFFu + ((u >> 16) & 1u)) >> 16;
  return (unsigned short)u;
}
DEVI float bf2f(unsigned short h) { return __uint_as_float(((unsigned int)h) << 16); }
DEVI void splitf(float v, unsigned short& hi, unsigned short& lo) {
  unsigned short h = f2bf(v);
  hi = h;
  lo = f2bf(v - bf2f(h));
}

#define GLD_LDS(gp, lp)                                                            \
  __builtin_amdgcn_global_load_lds((const __attribute__((address_space(1))) void*)(gp), \
                                   (__attribute__((address_space(3))) void*)(lp), 16, 0, 0)

// ------------------------------------------------------------------
// small kernels
// ------------------------------------------------------------------
__global__ void k_zero4(float* __restrict__ p, int n4) {
  int i = blockIdx.x * 256 + threadIdx.x;
  if (i < n4) ((float4*)p)[i] = float4{0.f, 0.f, 0.f, 0.f};
}

__global__ void k_cvt_pair(const float* __restrict__ src, unsigned short* __restrict__ hi,
                           unsigned short* __restrict__ lo, int n4) {
  int i = blockIdx.x * 256 + threadIdx.x;
  if (i >= n4) return;
  float4 v = ((const float4*)src)[i];
  ushort4 h, l;
  splitf(v.x, h.x, l.x);
  splitf(v.y, h.y, l.y);
  splitf(v.z, h.z, l.z);
  splitf(v.w, h.w, l.w);
  ((ushort4*)hi)[i] = h;
  ((ushort4*)lo)[i] = l;
}

// all 5 weight matrices in one dispatch (quad-indexed ranges)
__global__ void k_cvt_w(const float* __restrict__ W1, const float* __restrict__ W2,
                        const float* __restrict__ Wf1, const float* __restrict__ Wf2,
                        const float* __restrict__ Wf4, unsigned short* __restrict__ w1h,
                        unsigned short* __restrict__ w1l, unsigned short* __restrict__ w2h,
                        unsigned short* __restrict__ w2l, unsigned short* __restrict__ wf1h,
                        unsigned short* __restrict__ wf1l, unsigned short* __restrict__ wf2h,
                        unsigned short* __restrict__ wf2l, unsigned short* __restrict__ wf4h,
                        unsigned short* __restrict__ wf4l) {
  int gid = blockIdx.x * 256 + threadIdx.x;  // < 98304 quads
  const float* s;
  unsigned short *h, *l;
  int off;
  if (gid < 16384)      { s = W1;  h = w1h;  l = w1l;  off = 0; }
  else if (gid < 32768) { s = W2;  h = w2h;  l = w2l;  off = 16384; }
  else if (gid < 49152) { s = Wf1; h = wf1h; l = wf1l; off = 32768; }
  else if (gid < 65536) { s = Wf2; h = wf2h; l = wf2l; off = 49152; }
  else                  { s = Wf4; h = wf4h; l = wf4l; off = 65536; }
  int i = gid - off;
  float4 v = ((const float4*)s)[i];
  ushort4 hh, ll;
  splitf(v.x, hh.x, ll.x);
  splitf(v.y, hh.y, ll.y);
  splitf(v.z, hh.z, ll.z);
  splitf(v.w, hh.w, ll.w);
  ((ushort4*)h)[i] = hh;
  ((ushort4*)l)[i] = ll;
}

// read atomic fp32 accumulator (+optional relu), emit split bf16 (+optional fp32 copy)
template <int RELU, int WF32>
__global__ void k_red(const float* __restrict__ P, float* __restrict__ zf,
                      unsigned short* __restrict__ oh, unsigned short* __restrict__ ol) {
  int gid = blockIdx.x * 256 + threadIdx.x;  // < 8192*256
  float v = P[gid];
  if (RELU) v = fmaxf(v, 0.f);
  if (WF32) zf[gid] = v;
  unsigned short h, l;
  splitf(v, h, l);
  oh[gid] = h;
  ol[gid] = l;
}

__global__ void k_gather_sl(const int* __restrict__ last, const float* __restrict__ zf,
                            float* __restrict__ sl, unsigned short* __restrict__ slh,
                            unsigned short* __restrict__ sll, float* __restrict__ sg) {
  int b = blockIdx.x, t = threadIdx.x;
  float v = zf[(size_t)last[b] * 256 + t];
  sl[b * 256 + t] = v;
  unsigned short h, l;
  splitf(v, h, l);
  slh[b * 256 + t] = h;
  sll[b * 256 + t] = l;
  sg[b * 256 + t] = 0.f;  // zero the scatter-add target (fused zeroing)
}

// alpha = sigmoid(q1[idx[i]]+q2[i]) . Wf3 ; sg[idx[i]] += alpha * z[i]
__global__ void k_alpha(const int* __restrict__ idx, const float* __restrict__ q1s,
                        const float* __restrict__ q2, const float* __restrict__ w3,
                        const float* __restrict__ zf, float* __restrict__ sg) {
  int i = blockIdx.x * 4 + (threadIdx.x >> 6);
  int lane = threadIdx.x & 63;
  int seg = idx[i];
  int k = lane * 4;
  float4 a = *(const float4*)(q1s + (size_t)seg * 256 + k);
  float4 b = *(const float4*)(q2 + (size_t)i * 256 + k);
  float4 w = *(const float4*)(w3 + k);
  float s = w.x / (1.f + __expf(-(a.x + b.x))) + w.y / (1.f + __expf(-(a.y + b.y))) +
            w.z / (1.f + __expf(-(a.z + b.z))) + w.w / (1.f + __expf(-(a.w + b.w)));
#pragma unroll
  for (int o = 1; o < 64; o <<= 1) s += __shfl_xor(s, o);
  float4 z4 = *(const float4*)(zf + (size_t)i * 256 + k);
  float* d = sg + (size_t)seg * 256 + k;
  atomicAdd(d + 0, s * z4.x);
  atomicAdd(d + 1, s * z4.y);
  atomicAdd(d + 2, s * z4.z);
  atomicAdd(d + 3, s * z4.w);
}

__global__ void k_concat(const float* __restrict__ sl, const float* __restrict__ sg,
                         unsigned short* __restrict__ sh, unsigned short* __restrict__ slo) {
  int b = blockIdx.x, t = threadIdx.x;
  float v1 = sl[b * 256 + t];
  float v2 = sg[b * 256 + t];
  int o1 = b * 512 + t, o2 = o1 + 256;
  unsigned short h, l;
  splitf(v1, h, l); sh[o1] = h; slo[o1] = l;
  splitf(v2, h, l); sh[o2] = h; slo[o2] = l;
}

__global__ void k_smred(const float* __restrict__ pM, const float* __restrict__ pS,
                        float* __restrict__ mA, float* __restrict__ sA, int nt, int N) {
  __shared__ float lm[256], ls[256];
  int b = blockIdx.x;
  int t = threadIdx.x;
  float mx = -3.0e38f, sm = 0.f;
  for (int i = t; i < nt; i += 256) {
    float m = pM[(size_t)i * N + b];
    float s = pS[(size_t)i * N + b];
    if (m > mx) { sm = sm * __expf(mx - m) + s; mx = m; }
    else        { sm += s * __expf(m - mx); }
  }
  lm[t] = mx; ls[t] = sm;
  __syncthreads();
  for (int off = 128; off > 0; off >>= 1) {
    if (t < off) {
      float m2 = lm[t + off], s2 = ls[t + off];
      float mN = fmaxf(lm[t], m2);
      ls[t] = ls[t] * __expf(lm[t] - mN) + s2 * __expf(m2 - mN);
      lm[t] = mN;
    }
    __syncthreads();
  }
  if (t == 0) { mA[b] = lm[0]; sA[b] = ls[0]; }
}

__global__ void k_norm(float* __restrict__ out, const float* __restrict__ mA,
                       const float* __restrict__ sA) {
  size_t gid = (size_t)blockIdx.x * 256 + threadIdx.x;
  size_t e = gid * 4;
  int b = (int)(e / 100000);
  float m = mA[b];
  float inv = 1.0f / sA[b];
  float4 v = *(float4*)(out + e);
  v.x = __expf(v.x - m) * inv;
  v.y = __expf(v.y - m) * inv;
  v.z = __expf(v.z - m) * inv;
  v.w = __expf(v.w - m) * inv;
  *(float4*)(out + e) = v;
}

// ------------------------------------------------------------------
// GEMM: C[M,N] = A[M,K] @ B[N,K]^T
// 128x128 tile, BK=64, 4 waves (2x2 of 64x64), 16x16x32 MFMA,
// global_load_lds width-16 staging, XOR-swizzled LDS (<=2-way bank alias).
// AF32=1: A staged as raw fp32 (Af ptr), converted to bf16 (RNE) at
//         fragment-read time -> A is numerically exact at rounding time,
//         no pre-convert pass, no rank-1 correction needed.
// SWZ_ADJ: 1D grid 512 = {z[4] x m[64] x n[2]}, same-A-tile n-pair 8 apart
//          in linear ID -> same XCD L2.
// SWZ_FIN: 1D grid 3136 = {m[784] x n[4]}, same-A-tile n-quad on one XCD;
//          mtile >= ceil(M/128) blocks exit early.
// ------------------------------------------------------------------
template <int AF32, int ASPL, int BSPL, int OMODE, int HAS_BIAS, int GATHER, int SWZ>
__global__ __launch_bounds__(256, 2) void gemm_bt(
    const float* __restrict__ Af, const unsigned short* __restrict__ Ah,
    const unsigned short* __restrict__ Al, const unsigned short* __restrict__ Bh,
    const unsigned short* __restrict__ Bl, const float* __restrict__ bias,
    float* __restrict__ outF, unsigned short* __restrict__ outH,
    unsigned short* __restrict__ outL, float* __restrict__ pM, float* __restrict__ pS,
    const int* __restrict__ gidx, int M, int N, int lda, int ldb, long long ldo, int kStart,
    int kLen) {
  constexpr int LDS_SHORTS = AF32 ? 32768 : (2 + ASPL + BSPL) * 8192;
  __shared__ unsigned short lds[LDS_SHORTS];
  unsigned short* ldsA = lds;                                    // AF32: fp32 region (32 KB)
  unsigned short* ldsAl = lds + 8192;                            // valid iff ASPL
  unsigned short* ldsB = lds + (AF32 ? 16384 : (1 + ASPL) * 8192);
  unsigned short* ldsBl = ldsB + 8192;                           // valid iff BSPL

  const int tid = threadIdx.x;
  const int lane = tid & 63;
  const int wave = tid >> 6;
  const int wrow = wave >> 1;
  const int wcol = wave & 1;
  const int l15 = lane & 15;
  const int lkg = lane >> 4;

  int mtile, ntile, ztile;
  if constexpr (SWZ == SWZ_ADJ) {
    int id = blockIdx.x;                 // 512 blocks
    ztile = id >> 7;
    int r = id & 127;
    mtile = ((r >> 4) << 3) | (r & 7);   // n-pair (bit3) differs by 8 in id -> same XCD
    ntile = (r >> 3) & 1;
  } else if constexpr (SWZ == SWZ_FIN) {
    int id = blockIdx.x;                 // 3136 blocks
    mtile = ((id >> 5) << 3) | (id & 7); // n-quad (bits 3..4) strides 8 -> same XCD
    ntile = (id >> 3) & 3;
    ztile = 0;
    if (mtile >= ((M + 127) >> 7)) return;
  } else {
    mtile = blockIdx.y;
    ntile = blockIdx.x;
    ztile = blockIdx.z;
  }
  const int m0 = mtile * 128;
  const int n0 = ntile * 128;
  const int ks = kStart + ztile * kLen;

  // hoisted row indices for staging
  int ga[8], gb[4];
  if constexpr (AF32) {
#pragma unroll
    for (int c = 0; c < 8; ++c) {
      int row = (c * 256 + tid) >> 4;
      int ra = m0 + row;
      if (ra >= M) ra = M - 1;
      ga[c] = ra;
    }
  } else {
#pragma unroll
    for (int c = 0; c < 4; ++c) {
      int row = (c * 256 + tid) >> 3;
      int ra = m0 + row;
      if (ra >= M) ra = M - 1;
      ga[c] = GATHER ? gidx[ra] : ra;
    }
  }
#pragma unroll
  for (int c = 0; c < 4; ++c) gb[c] = n0 + ((c * 256 + tid) >> 3);

  f32x4 acc[4][4];
#pragma unroll
  for (int a = 0; a < 4; ++a)
#pragma unroll
    for (int b = 0; b < 4; ++b) acc[a][b] = f32x4{0.f, 0.f, 0.f, 0.f};

  for (int k0 = ks; k0 < ks + kLen; k0 += 64) {
    // ---- stage A
    if constexpr (AF32) {
      // fp32: slot (row, kc[16]) of 4 floats holds global chunk (kc ^ (row&15))
#pragma unroll
      for (int c = 0; c < 8; ++c) {
        int s = c * 256 + tid;
        int row = s >> 4;
        int kc = s & 15;
        int kel = k0 + ((kc ^ (row & 15)) << 2);
        GLD_LDS(Af + (size_t)ga[c] * lda + kel, ldsA + ((c * 256 + wave * 64) << 3));
      }
    } else {
      // bf16: slot (row, kc[8]) of 8 shorts holds global chunk (kc ^ (row&7))
#pragma unroll
      for (int c = 0; c < 4; ++c) {
        int s = c * 256 + tid;
        int row = s >> 3;
        int kc = s & 7;
        int kel = k0 + ((kc ^ (row & 7)) << 3);
        int lofs = (c * 256 + wave * 64) << 3;
        GLD_LDS(Ah + (size_t)ga[c] * lda + kel, ldsA + lofs);
        if (ASPL) GLD_LDS(Al + (size_t)ga[c] * lda + kel, ldsAl + lofs);
      }
    }
    // ---- stage B (always split bf16)
#pragma unroll
    for (int c = 0; c < 4; ++c) {
      int s = c * 256 + tid;
      int row = s >> 3;
      int kc = s & 7;
      int kel = k0 + ((kc ^ (row & 7)) << 3);
      int lofs = (c * 256 + wave * 64) << 3;
      GLD_LDS(Bh + (size_t)gb[c] * ldb + kel, ldsB + lofs);
      if (BSPL) GLD_LDS(Bl + (size_t)gb[c] * ldb + kel, ldsBl + lofs);
    }
    __syncthreads();  // drains vmcnt (LDS-DMA) + orders vs compute
    // ---- compute
#pragma unroll
    for (int kk = 0; kk < 2; ++kk) {
      bf16x8 fa[4], fb[4], fal[4], fbl[4];
#pragma unroll
      for (int t = 0; t < 4; ++t) {
        int mm = (wrow << 6) + (t << 4) + l15;
        if constexpr (AF32) {
          const float* fp = (const float*)ldsA;
          int c0 = (kk << 3) + (lkg << 1);
          f32x4 a0 = *(const f32x4*)(fp + (((mm << 4) + (c0 ^ (mm & 15))) << 2));
          f32x4 a1 = *(const f32x4*)(fp + (((mm << 4) + ((c0 + 1) ^ (mm & 15))) << 2));
          bf16x8 r;
          r[0] = (__bf16)a0[0]; r[1] = (__bf16)a0[1]; r[2] = (__bf16)a0[2]; r[3] = (__bf16)a0[3];
          r[4] = (__bf16)a1[0]; r[5] = (__bf16)a1[1]; r[6] = (__bf16)a1[2]; r[7] = (__bf16)a1[3];
          fa[t] = r;
        } else {
          int kc = (kk << 2) + lkg;
          int sa = ((mm << 3) + (kc ^ (mm & 7))) << 3;
          fa[t] = *(const bf16x8*)(ldsA + sa);
          if (ASPL) fal[t] = *(const bf16x8*)(ldsAl + sa);
        }
        int nn = (wcol << 6) + (t << 4) + l15;
        int kc = (kk << 2) + lkg;
        int sb = ((nn << 3) + (kc ^ (nn & 7))) << 3;
        fb[t] = *(const bf16x8*)(ldsB + sb);
        if (BSPL) fbl[t] = *(const bf16x8*)(ldsBl + sb);
      }
#pragma unroll
      for (int tm = 0; tm < 4; ++tm)
#pragma unroll
        for (int tn = 0; tn < 4; ++tn) {
          acc[tm][tn] = __builtin_amdgcn_mfma_f32_16x16x32_bf16(fa[tm], fb[tn], acc[tm][tn], 0, 0, 0);
          if (BSPL)
            acc[tm][tn] = __builtin_amdgcn_mfma_f32_16x16x32_bf16(fa[tm], fbl[tn], acc[tm][tn], 0, 0, 0);
          if (ASPL && !AF32)
            acc[tm][tn] = __builtin_amdgcn_mfma_f32_16x16x32_bf16(fal[tm], fb[tn], acc[tm][tn], 0, 0, 0);
        }
    }
    __syncthreads();
  }

  // ---- epilogue. C/D layout: col = lane&15 (N), row = (lane>>4)*4 + reg (M)
  const int mb = m0 + (wrow << 6);
  const int nb = n0 + (wcol << 6);

  if constexpr (OMODE == OM_ATOM) {
#pragma unroll
    for (int tm = 0; tm < 4; ++tm) {
      const int mg = mb + (tm << 4) + (lkg << 2);
#pragma unroll
      for (int tn = 0; tn < 4; ++tn) {
        const int ng = nb + (tn << 4) + l15;
#pragma unroll
        for (int r = 0; r < 4; ++r) atomicAdd(outF + (size_t)(mg + r) * N + ng, acc[tm][tn][r]);
      }
    }
  } else if constexpr (OMODE == OM_F32) {
#pragma unroll
    for (int tm = 0; tm < 4; ++tm) {
      const int mg = mb + (tm << 4) + (lkg << 2);
#pragma unroll
      for (int tn = 0; tn < 4; ++tn) {
        const int ng = nb + (tn << 4) + l15;
        const float bv = HAS_BIAS ? bias[ng] : 0.f;
#pragma unroll
        for (int r = 0; r < 4; ++r)
          outF[(size_t)(mg + r) * (size_t)ldo + ng] = acc[tm][tn][r] + bv;
      }
    }
  } else if constexpr (OMODE == OM_BF16) {
#pragma unroll
    for (int tm = 0; tm < 4; ++tm) {
      const int mg = mb + (tm << 4) + (lkg << 2);
#pragma unroll
      for (int tn = 0; tn < 4; ++tn) {
        const int ng = nb + (tn << 4) + l15;
        const float bv = HAS_BIAS ? bias[ng] : 0.f;
#pragma unroll
        for (int r = 0; r < 4; ++r) {
          unsigned short h, l;
          splitf(acc[tm][tn][r] + bv, h, l);
          outH[(size_t)(mg + r) * (size_t)ldo + ng] = h;
          outL[(size_t)(mg + r) * (size_t)ldo + ng] = l;
        }
      }
    }
  } else if constexpr (OMODE == OM_BF16T) {
    // write transposed: out[n][m], reg r -> 4 consecutive m
#pragma unroll
    for (int tn = 0; tn < 4; ++tn) {
      const int ng = nb + (tn << 4) + l15;
      const float bv = HAS_BIAS ? bias[ng] : 0.f;
#pragma unroll
      for (int tm = 0; tm < 4; ++tm) {
        const int m4 = mb + (tm << 4) + (lkg << 2);
        ushort4 h4, l4;
        splitf(acc[tm][tn][0] + bv, h4.x, l4.x);
        splitf(acc[tm][tn][1] + bv, h4.y, l4.y);
        splitf(acc[tm][tn][2] + bv, h4.z, l4.z);
        splitf(acc[tm][tn][3] + bv, h4.w, l4.w);
        *(ushort4*)(outH + (size_t)ng * (size_t)ldo + m4) = h4;
        *(ushort4*)(outL + (size_t)ng * (size_t)ldo + m4) = l4;
      }
    }
  } else if constexpr (OMODE == OM_SMST) {
    // store raw logits transposed: outF[b][i] (ldo = M stride of out rows),
    // plus per-(mtile, col) online-softmax partials {max, sumexp}.
    float cm[4], cs[4];
#pragma unroll
    for (int tn = 0; tn < 4; ++tn) {
      const int ng = nb + (tn << 4) + l15;
#pragma unroll
      for (int tm = 0; tm < 4; ++tm) {
        const int m4 = mb + (tm << 4) + (lkg << 2);
        if (m4 < M) {
          float4 v4 = {acc[tm][tn][0], acc[tm][tn][1], acc[tm][tn][2], acc[tm][tn][3]};
          *(float4*)(outF + (size_t)ng * (size_t)ldo + m4) = v4;
        }
      }
      float mx = -3.0e38f;
#pragma unroll
      for (int tm = 0; tm < 4; ++tm) {
        const int m4 = mb + (tm << 4) + (lkg << 2);
        if (m4 < M) {
#pragma unroll
          for (int r = 0; r < 4; ++r) mx = fmaxf(mx, acc[tm][tn][r]);
        }
      }
      mx = fmaxf(mx, __shfl_xor(mx, 16));
      mx = fmaxf(mx, __shfl_xor(mx, 32));
      float sm = 0.f;
#pragma unroll
      for (int tm = 0; tm < 4; ++tm) {
        const int m4 = mb + (tm << 4) + (lkg << 2);
        if (m4 < M) {
#pragma unroll
          for (int r = 0; r < 4; ++r) sm += __expf(acc[tm][tn][r] - mx);
        }
      }
      sm += __shfl_xor(sm, 16);
      sm += __shfl_xor(sm, 32);
      cm[tn] = mx;
      cs[tn] = sm;
    }
    float* sf = (float*)lds;  // LDS free after last loop barrier
    if (lkg == 0) {
#pragma unroll
      for (int tn = 0; tn < 4; ++tn) {
        int col = (wcol << 6) + (tn << 4) + l15;
        sf[(wrow << 7) + col] = cm[tn];
        sf[256 + (wrow << 7) + col] = cs[tn];
      }
    }
    __syncthreads();
    if (tid < 128) {
      float ma = sf[tid], mb2 = sf[128 + tid];
      float sa2 = sf[256 + tid], sb2 = sf[384 + tid];
      float mv = fmaxf(ma, mb2);
      float sv = sa2 * __expf(ma - mv) + sb2 * __expf(mb2 - mv);
      pM[(size_t)mtile * N + n0 + tid] = mv;
      pS[(size_t)mtile * N + n0 + tid] = sv;
    }
  }
}

// ------------------------------------------------------------------
extern "C" void kernel_launch(void* const* d_in, const int* in_sizes, int n_in, void* d_out,
                              int out_size, void* d_ws, size_t ws_size, hipStream_t stream) {
  (void)in_sizes; (void)n_in; (void)out_size;
  const float* adj = (const float*)d_in[0];
  const int* items = (const int*)d_in[1];
  const int* last = (const int*)d_in[2];
  const int* idx = (const int*)d_in[3];
  const float* emb = (const float*)d_in[4];
  const float* W1 = (const float*)d_in[5];
  const float* b1 = (const float*)d_in[6];
  const float* W2 = (const float*)d_in[7];
  const float* b2 = (const float*)d_in[8];
  const float* Wf1 = (const float*)d_in[9];
  const float* bf1 = (const float*)d_in[10];
  const float* Wf2 = (const float*)d_in[11];
  const float* bf2 = (const float*)d_in[12];
  const float* Wf3 = (const float*)d_in[13];
  const float* Wf4 = (const float*)d_in[14];
  const float* bf4 = (const float*)d_in[15];
  float* out = (float*)d_out;

  char* base = (char*)d_ws;
  size_t used = 0;
  auto alloc = [&](size_t bytes) -> char* {
    char* r = base + used;
    used += (bytes + 255) & ~(size_t)255;
    return r;
  };
  unsigned short* embh = (unsigned short*)alloc((size_t)100000 * 256 * 2);
  unsigned short* embl = (unsigned short*)alloc((size_t)100000 * 256 * 2);
  // --- contiguous zero-init region: hpre, zpre
  float* hpre = (float*)alloc((size_t)8192 * 256 * 4);
  float* zpre = (float*)alloc((size_t)8192 * 256 * 4);
  // ---
  unsigned short* w1h = (unsigned short*)alloc(65536 * 2);
  unsigned short* w1l = (unsigned short*)alloc(65536 * 2);
  unsigned short* w2h = (unsigned short*)alloc(65536 * 2);
  unsigned short* w2l = (unsigned short*)alloc(65536 * 2);
  unsigned short* wf1h = (unsigned short*)alloc(65536 * 2);
  unsigned short* wf1l = (unsigned short*)alloc(65536 * 2);
  unsigned short* wf2h = (unsigned short*)alloc(65536 * 2);
  unsigned short* wf2l = (unsigned short*)alloc(65536 * 2);
  unsigned short* wf4h = (unsigned short*)alloc(131072 * 2);
  unsigned short* wf4l = (unsigned short*)alloc(131072 * 2);
  unsigned short* y1Th = (unsigned short*)alloc((size_t)256 * 8192 * 2);
  unsigned short* y1Tl = (unsigned short*)alloc((size_t)256 * 8192 * 2);
  unsigned short* y2Th = (unsigned short*)alloc((size_t)256 * 8192 * 2);
  unsigned short* y2Tl = (unsigned short*)alloc((size_t)256 * 8192 * 2);
  unsigned short* hh = (unsigned short*)alloc((size_t)8192 * 256 * 2);
  unsigned short* hl = (unsigned short*)alloc((size_t)8192 * 256 * 2);
  float* zf = (float*)alloc((size_t)8192 * 256 * 4);
  unsigned short* zh = (unsigned short*)alloc((size_t)8192 * 256 * 2);
  unsigned short* zl = (unsigned short*)alloc((size_t)8192 * 256 * 2);
  float* q1s = (float*)alloc((size_t)512 * 256 * 4);
  float* q2 = (float*)alloc((size_t)8192 * 256 * 4);
  float* sl = (float*)alloc((size_t)512 * 256 * 4);
  unsigned short* slh = (unsigned short*)alloc((size_t)512 * 256 * 2);
  unsigned short* sll = (unsigned short*)alloc((size_t)512 * 256 * 2);
  float* sg = (float*)alloc((size_t)512 * 256 * 4);
  unsigned short* s_h = (unsigned short*)alloc((size_t)512 * 512 * 2);
  unsigned short* s_l = (unsigned short*)alloc((size_t)512 * 512 * 2);
  unsigned short* shh = (unsigned short*)alloc((size_t)512 * 256 * 2);
  unsigned short* shl = (unsigned short*)alloc((size_t)512 * 256 * 2);
  float* pMx = (float*)alloc((size_t)782 * 512 * 4);
  float* pSx = (float*)alloc((size_t)782 * 512 * 4);
  float* mA = (float*)alloc(512 * 4);
  float* sA = (float*)alloc(512 * 4);
  if (used > ws_size) return;  // insufficient workspace: bail (bench will flag)

  // zero hpre+zpre (contiguous, 1048576 float4s = 16.8 MB)
  k_zero4<<<4096, 256, 0, stream>>>(hpre, 1048576);
  // conversions
  k_cvt_pair<<<25000, 256, 0, stream>>>(emb, embh, embl, 6400000);
  k_cvt_w<<<384, 256, 0, stream>>>(W1, W2, Wf1, Wf2, Wf4, w1h, w1l, w2h, w2l, wf1h, wf1l, wf2h,
                                   wf2l, wf4h, wf4l);

  // y1^T = (emb[items]@W1^T + b1)^T  [256 x 8192], gather fused into A-staging
  gemm_bt<0, 1, 1, OM_BF16T, 1, 1, SWZ_NONE><<<dim3(2, 64, 1), 256, 0, stream>>>(
      nullptr, embh, embl, w1h, w1l, b1, nullptr, y1Th, y1Tl, nullptr, nullptr, items, 8192, 256,
      256, 256, 8192, 0, 256);
  // h_pre = adj @ y1 (split-K=4, atomic fp32 accumulate, fp32 A w/ in-reg cvt)
  gemm_bt<1, 0, 1, OM_ATOM, 0, 0, SWZ_ADJ><<<512, 256, 0, stream>>>(
      adj, nullptr, nullptr, y1Th, y1Tl, nullptr, hpre, nullptr, nullptr, nullptr, nullptr,
      nullptr, 8192, 256, 8192, 8192, 0, 0, 2048);
  k_red<1, 0><<<8192, 256, 0, stream>>>(hpre, nullptr, hh, hl);  // h = relu(...)
  // y2^T = (h@W2^T + b2)^T
  gemm_bt<0, 1, 1, OM_BF16T, 1, 0, SWZ_NONE><<<dim3(2, 64, 1), 256, 0, stream>>>(
      nullptr, hh, hl, w2h, w2l, b2, nullptr, y2Th, y2Tl, nullptr, nullptr, nullptr, 8192, 256,
      256, 256, 8192, 0, 256);
  // z_pre = adj @ y2 (split-K=4, atomic, fp32 A)
  gemm_bt<1, 0, 1, OM_ATOM, 0, 0, SWZ_ADJ><<<512, 256, 0, stream>>>(
      adj, nullptr, nullptr, y2Th, y2Tl, nullptr, zpre, nullptr, nullptr, nullptr, nullptr,
      nullptr, 8192, 256, 8192, 8192, 0, 0, 2048);
  k_red<0, 1><<<8192, 256, 0, stream>>>(zpre, zf, zh, zl);

  k_gather_sl<<<512, 256, 0, stream>>>(last, zf, sl, slh, sll, sg);
  // q1 = sl@Wf1^T + bf1 ; q2 = z@Wf2^T + bf2
  gemm_bt<0, 1, 1, OM_F32, 1, 0, SWZ_NONE><<<dim3(2, 4, 1), 256, 0, stream>>>(
      nullptr, slh, sll, wf1h, wf1l, bf1, q1s, nullptr, nullptr, nullptr, nullptr, nullptr, 512,
      256, 256, 256, 256, 0, 256);
  gemm_bt<0, 1, 1, OM_F32, 1, 0, SWZ_NONE><<<dim3(2, 64, 1), 256, 0, stream>>>(
      nullptr, zh, zl, wf2h, wf2l, bf2, q2, nullptr, nullptr, nullptr, nullptr, nullptr, 8192,
      256, 256, 256, 256, 0, 256);
  k_alpha<<<2048, 256, 0, stream>>>(idx, q1s, q2, Wf3, zf, sg);
  k_concat<<<512, 256, 0, stream>>>(sl, sg, s_h, s_l);
  // sh = [sl|sg]@Wf4^T + bf4  -> split bf16 [512 x 256]
  gemm_bt<0, 1, 1, OM_BF16, 1, 0, SWZ_NONE><<<dim3(2, 4, 1), 256, 0, stream>>>(
      nullptr, s_h, s_l, wf4h, wf4l, bf4, nullptr, shh, shl, nullptr, nullptr, nullptr, 512, 256,
      512, 512, 256, 0, 512);
  // logits = emb @ sh^T, stored transposed fp32 into out + softmax partials
  gemm_bt<0, 1, 1, OM_SMST, 0, 0, SWZ_FIN><<<3136, 256, 0, stream>>>(
      nullptr, embh, embl, shh, shl, nullptr, out, nullptr, nullptr, pMx, pSx, nullptr, 100000,
      512, 256, 256, 100000, 0, 256);
  k_smred<<<512, 256, 0, stream>>>(pMx, pSx, mA, sA, 782, 512);
  k_norm<<<50000, 256, 0, stream>>>(out, mA, sA);
}